// Round 4
// baseline (290.167 us; speedup 1.0000x reference)
//
#include <hip/hip_runtime.h>
#include <cstdint>
#include <cstddef>

// Problem constants (reference: B=4, T=4096, E=1024, M=E/2=512)
#define Tdim 4096
#define Bdim 4
#define Edim 1024
#define Mdim 512
#define EPSF 1e-6f

typedef __bf16 bf16x8 __attribute__((ext_vector_type(8)));
typedef float f32x4 __attribute__((ext_vector_type(4)));

// float -> bf16 bits, round-to-nearest-even (used in extract path)
__device__ __forceinline__ unsigned short f2bf(float f) {
  union { float f; unsigned int u; } a; a.f = f;
  unsigned int r = a.u + 0x7fffu + ((a.u >> 16) & 1u);
  return (unsigned short)(r >> 16);
}

// pack two f32 -> bf16x2 (round-half-up; 0.5-ulp bound, ties negligible here)
__device__ __forceinline__ unsigned int pack_bf16(float a, float b) {
  union { float f; unsigned int u; } ua, ub; ua.f = a; ub.f = b;
  // dst bytes [0,1,2,3] = [a.b2, a.b3, b.b2, b.b3]
  return __builtin_amdgcn_perm(ub.u + 0x8000u, ua.u + 0x8000u, 0x07060302u);
}

// bump kernel g(u) = exp(1 - 1/(1-u^2+eps)); reference's u>=1-EPS clamp can
// never fire for j<=T-1 (u_max = 1 - 1/horizon), so it is omitted.
__device__ __forceinline__ float kernel_g(float dj, float inv_h) {
  float u = fminf(dj * inv_h, 1.0f - EPSF);
  return __expf(1.0f - 1.0f / (1.0f - u * u + EPSF));
}

typedef void __attribute__((address_space(1)))* gas1;
typedef void __attribute__((address_space(3)))* las3;
// async global->LDS, 16B per lane; LDS dest = wave-uniform base + lane*16
__device__ __forceinline__ void load_lds16(const void* g, void* l) {
  __builtin_amdgcn_global_load_lds((gas1)(g), (las3)(l), 16, 0, 0);
}

// ---------------- prep kernels ----------------

__global__ __launch_bounds__(256) void gate_kernel(const float* __restrict__ graw,
                                                   float* __restrict__ gate) {
  const int m = blockIdx.x * 256 + threadIdx.x;
  if (m < Mdim) {
    const float v = graw[m];
    gate[m] = fmaxf(v, 0.0f) + log1pf(__expf(-fabsf(v)));  // stable softplus
  }
}

__global__ __launch_bounds__(256) void rowsum_kernel(float* __restrict__ inv_rowsum) {
  const int i = blockIdx.x;
  const int tid = threadIdx.x;
  const float inv_h = 1.0f / (float)(Tdim - i);
  float s = 0.0f;
  for (int j = i + tid; j < Tdim; j += 256)
    s += kernel_g((float)(j - i), inv_h);
#pragma unroll
  for (int off = 32; off; off >>= 1) s += __shfl_down(s, off);
  __shared__ float red[4];
  if ((tid & 63) == 0) red[tid >> 6] = s;
  __syncthreads();
  if (tid == 0) inv_rowsum[i] = 1.0f / (red[0] + red[1] + red[2] + red[3]);
}

// XcT[b][m][j] = bf16(x[b][j][2m])  (transposed so GEMM B-frag is k-contiguous)
// tile: 64 j x 32 m per block. grid (T/64, M/32, B)
__global__ __launch_bounds__(256) void extract_kernel(const float* __restrict__ x,
                                                      unsigned short* __restrict__ XcT) {
  __shared__ unsigned short Ls[32][68];
  const int j0 = blockIdx.x * 64;
  const int m0 = blockIdx.y * 32;
  const int b  = blockIdx.z;
  const int tid = threadIdx.x;
  const int q = tid & 15;        // float4 chunk along e
  const int jbase = tid >> 4;    // 0..15
#pragma unroll
  for (int it = 0; it < 4; ++it) {
    const int jj = jbase + it * 16;
    const size_t off = ((size_t)(b * Tdim + j0 + jj)) * Edim + 2 * m0 + 4 * q;
    const float4 v = *reinterpret_cast<const float4*>(&x[off]);
    Ls[2 * q][jj]     = f2bf(v.x);   // even channel of m0+2q
    Ls[2 * q + 1][jj] = f2bf(v.z);   // even channel of m0+2q+1
  }
  __syncthreads();
  const int ch = tid & 15;
  const int mb = tid >> 4;
#pragma unroll
  for (int it = 0; it < 2; ++it) {
    const int m = mb + it * 16;
    ushort4 uv;
    uv.x = Ls[m][4 * ch];
    uv.y = Ls[m][4 * ch + 1];
    uv.z = Ls[m][4 * ch + 2];
    uv.w = Ls[m][4 * ch + 3];
    *reinterpret_cast<ushort4*>(
        &XcT[((size_t)(b * Mdim + m0 + m)) * Tdim + j0 + 4 * ch]) = uv;
  }
}

// ---------------- GEMM with fused analytic K-generation ----------------
// phi[b,i,m] = K[i,:] @ Xc[b,:,m]; K never materialized: each K-tile (128i x
// 64j, bf16) is computed in-register (each thread: 1 row, 32 consecutive j)
// and ds_written to LDS with the XOR swizzle (16B slot s of row r holds
// logical chunk s^(r&7)). B-tile (XcT) staged via global_load_lds (source-
// permuted swizzle), double-buffered. Per-iter schedule:
//   bar1 (prev MFMA done -> safe to overwrite As)
//   issue next B-tile loads; compute A-tile (~900 VALU cyc hides B latency)
//   bar2 (A ds_writes visible; B drained)
//   MFMA
// Triangular-imbalance fix: 1-D grid, anti-length pairing: ids c and c+256
// get p and 31-p, so any mod-256 round-robin gives every CU exactly 66
// iterations ((64-2p)+(64-2(31-p)) = 66).
// Diagonal masking peeled: only the first 2 j-tiles of a block contain j<i;
// mask uses integer dj (float u can round to -eps at j==i, which would zero
// K(T-1,T-1)=1 and break the last rows).
__global__ __launch_bounds__(256) void gemm_kernel(
    const unsigned short* __restrict__ XcT,
    const float* __restrict__ inv_rowsum,
    const float* __restrict__ x,
    const float* __restrict__ gate,
    float* __restrict__ out) {
  const int id = blockIdx.x;           // 0..511
  int p, mb;
  if (id < 256) { p = id & 31; mb = id >> 5; }
  else          { p = 31 - (id & 31); mb = 8 + ((id - 256) >> 5); }
  const int i0 = p * 128;
  const int m0 = (mb & 3) * 128;
  const int b  = mb >> 2;

  __shared__ unsigned short As[128 * 64];     // K tile, swizzled, single buffer
  __shared__ unsigned short Bs[2][128 * 64];  // XcT tile, swizzled, dbuf
  const int tid = threadIdx.x;
  const int w = tid >> 6;
  const int l = tid & 63;
  f32x4 acc[4][4] = {};
  const int wr = w >> 1, wc = w & 1;
  const unsigned short* Brow = XcT + ((size_t)b * Mdim + m0) * Tdim;
  const int srow  = l >> 3;                   // B-stage: row within 8-row group
  const int sslot = l & 7;                    // linear 16B slot this lane fills
  const int schunk = (sslot ^ srow) * 8;      // swizzled source chunk (bf16 units)

  // A-gen per-thread constants: one row, one 32-j half
  const int r = tid >> 1;                     // row 0..127
  const int h = tid & 1;                      // j-half (0: j+0..31, 1: j+32..63)
  const int i = i0 + r;
  const float inv_h = __fdividef(1.0f, (float)(Tdim - i));
  const float crow  = 2.7182818284590452f * inv_rowsum[i];  // e * inv_s[i]
  unsigned int* Aw = reinterpret_cast<unsigned int*>(As);   // dword view

  // preload first B tile into buffer 0
#pragma unroll
  for (int t = 0; t < 4; ++t) {
    const int rr = (w * 4 + t) * 8 + srow;
    load_lds16(Brow + (size_t)rr * Tdim + (i0 + schunk), &Bs[0][(w * 4 + t) * 512]);
  }

  const int lr16 = l & 15;
  const int kq = l >> 4;  // 0..3: which 16B chunk quarter of the k-dim
  const int niter = (Tdim - i0) >> 6;
  for (int jt = 0; jt < niter; ++jt) {
    const int j0 = i0 + jt * 64;
    const int cur = jt & 1;
    __syncthreads();  // bar1: prev MFMA done; B(jt) resident (drained earlier)
    if (jt + 1 < niter) {  // issue next B tile under the A-gen compute
      const int jn = j0 + 64;
#pragma unroll
      for (int t = 0; t < 4; ++t) {
        const int rr = (w * 4 + t) * 8 + srow;
        load_lds16(Brow + (size_t)rr * Tdim + (jn + schunk), &Bs[cur ^ 1][(w * 4 + t) * 512]);
      }
    }
    // ---- analytic A-tile: K[i][j] = e*inv_s * exp(-1/(1-u^2+eps)), u=(j-i)/(T-i)
    {
      const int dj0 = j0 + h * 32 - i;
      const float u0 = (float)dj0 * inv_h;
      const bool diag = (jt < 2);  // only first 2 tiles contain j < i
#pragma unroll
      for (int cc = 0; cc < 4; ++cc) {
        float v[8];
#pragma unroll
        for (int k = 0; k < 8; ++k) {
          const int e = cc * 8 + k;
          const float u = fmaf((float)e, inv_h, u0);
          const float d = fmaf(-u, u, 1.000001f);       // 1 - u^2 + eps
          const float rr = __fdividef(1.0f, d);
          float val = crow * __expf(-rr);
          if (diag && (dj0 + e) < 0) val = 0.0f;        // exact sub-diagonal mask
          v[k] = val;
        }
        uint4 pk;
        pk.x = pack_bf16(v[0], v[1]);
        pk.y = pack_bf16(v[2], v[3]);
        pk.z = pack_bf16(v[4], v[5]);
        pk.w = pack_bf16(v[6], v[7]);
        const int slot = ((h * 4 + cc) ^ (r & 7));
        *reinterpret_cast<uint4*>(&Aw[r * 32 + slot * 4]) = pk;  // 16B ds_write
      }
    }
    __syncthreads();  // bar2: A visible; next-B drained (hidden under A-gen)
#pragma unroll
    for (int kk = 0; kk < 2; ++kk) {
      bf16x8 af[4], bfr[4];
      const int chunk = kk * 4 + kq;
      const int slot = (chunk ^ (lr16 & 7)) * 8;   // un-swizzle
#pragma unroll
      for (int rr2 = 0; rr2 < 4; ++rr2)
        af[rr2] = *reinterpret_cast<const bf16x8*>(&As[(wr * 64 + rr2 * 16 + lr16) * 64 + slot]);
#pragma unroll
      for (int c = 0; c < 4; ++c)
        bfr[c] = *reinterpret_cast<const bf16x8*>(&Bs[cur][(wc * 64 + c * 16 + lr16) * 64 + slot]);
#pragma unroll
      for (int rr2 = 0; rr2 < 4; ++rr2)
#pragma unroll
        for (int c = 0; c < 4; ++c)
          acc[rr2][c] = __builtin_amdgcn_mfma_f32_16x16x32_bf16(af[rr2], bfr[c], acc[rr2][c], 0, 0, 0);
    }
  }

  // fused epilogue: C/D layout col=lane&15 (m), row=(lane>>4)*4+reg (i).
  // out even = x even (exact fp32 passthrough), odd = phi*gate.
  const int lr = l & 15;
  const int lq = l >> 4;
#pragma unroll
  for (int rr2 = 0; rr2 < 4; ++rr2) {
    const int ii = i0 + wr * 64 + rr2 * 16 + lq * 4;
#pragma unroll
    for (int c = 0; c < 4; ++c) {
      const int m = m0 + wc * 64 + c * 16 + lr;
      const float gm = gate[m];
#pragma unroll
      for (int v = 0; v < 4; ++v) {
        const size_t o = ((size_t)(b * Tdim + ii + v)) * Edim + 2 * m;
        const float2 xv = *reinterpret_cast<const float2*>(&x[o]);
        float2 res;
        res.x = xv.x;
        res.y = acc[rr2][c][v] * gm;
        *reinterpret_cast<float2*>(&out[o]) = res;
      }
    }
  }
}

// ---------------- slow-but-correct fallback (only if ws too small) ----------------
__global__ __launch_bounds__(256) void fallback_kernel(const float* __restrict__ x,
                                                       const float* __restrict__ graw,
                                                       float* __restrict__ out) {
  const int i = blockIdx.x, b = blockIdx.y, tid = threadIdx.x;
  const float inv_h = 1.0f / (float)(Tdim - i);
  float s = 0.0f;
  for (int j = i + tid; j < Tdim; j += 256)
    s += kernel_g((float)(j - i), inv_h);
#pragma unroll
  for (int off = 32; off; off >>= 1) s += __shfl_down(s, off);
  __shared__ float red[4];
  __shared__ float sinv_sh;
  if ((tid & 63) == 0) red[tid >> 6] = s;
  __syncthreads();
  if (tid == 0) sinv_sh = 1.0f / (red[0] + red[1] + red[2] + red[3]);
  __syncthreads();
  const float sinv = sinv_sh;
  const float* xb = x + (size_t)b * Tdim * Edim;
  float a0 = 0.0f, a1 = 0.0f;
  const int m0 = tid, m1 = tid + 256;
  for (int j = i; j < Tdim; ++j) {
    const float wgt = kernel_g((float)(j - i), inv_h);
    const float* xr = xb + (size_t)j * Edim;
    a0 += wgt * xr[2 * m0];
    a1 += wgt * xr[2 * m1];
  }
  const float v0 = graw[m0], v1 = graw[m1];
  const float g0 = fmaxf(v0, 0.0f) + log1pf(__expf(-fabsf(v0)));
  const float g1 = fmaxf(v1, 0.0f) + log1pf(__expf(-fabsf(v1)));
  const size_t o = ((size_t)(b * Tdim + i)) * Edim;
  const float* xi = xb + (size_t)i * Edim;
  out[o + 2 * m0]     = xi[2 * m0];
  out[o + 2 * m0 + 1] = a0 * sinv * g0;
  out[o + 2 * m1]     = xi[2 * m1];
  out[o + 2 * m1 + 1] = a1 * sinv * g1;
}

extern "C" void kernel_launch(void* const* d_in, const int* in_sizes, int n_in,
                              void* d_out, int out_size, void* d_ws, size_t ws_size,
                              hipStream_t stream) {
  const float* x = (const float*)d_in[0];
  // d_in[1] is the triu mask: always upper-triangular by construction; folded analytically.
  const float* gate_raw = (const float*)d_in[2];
  float* out = (float*)d_out;

  const size_t XcT_bytes = (size_t)Bdim * Mdim * Tdim * 2;  // 16 MiB
  const size_t need = XcT_bytes + (size_t)(Tdim + Mdim) * sizeof(float);

  if (ws_size < need) {
    fallback_kernel<<<dim3(Tdim, Bdim), 256, 0, stream>>>(x, gate_raw, out);
    return;
  }

  char* ws = (char*)d_ws;
  unsigned short* XcT  = (unsigned short*)ws;
  float* inv_rowsum    = (float*)(ws + XcT_bytes);
  float* gate          = inv_rowsum + Tdim;

  gate_kernel<<<dim3((Mdim + 255) / 256), 256, 0, stream>>>(gate_raw, gate);
  rowsum_kernel<<<dim3(Tdim), 256, 0, stream>>>(inv_rowsum);
  extract_kernel<<<dim3(Tdim / 64, Mdim / 32, Bdim), 256, 0, stream>>>(x, XcT);
  gemm_kernel<<<dim3(512), 256, 0, stream>>>(XcT, inv_rowsum, x, gate, out);
}

// Round 5
// 227.916 us; speedup vs baseline: 1.2731x; 1.2731x over previous
//
#include <hip/hip_runtime.h>
#include <cstdint>
#include <cstddef>

// Problem constants (reference: B=4, T=4096, E=1024, M=E/2=512)
#define Tdim 4096
#define Bdim 4
#define Edim 1024
#define Mdim 512
#define EPSF 1e-6f

typedef __bf16 bf16x8 __attribute__((ext_vector_type(8)));
typedef float f32x4 __attribute__((ext_vector_type(4)));

// float -> bf16 bits, round-to-nearest-even (used in extract path)
__device__ __forceinline__ unsigned short f2bf(float f) {
  union { float f; unsigned int u; } a; a.f = f;
  unsigned int r = a.u + 0x7fffu + ((a.u >> 16) & 1u);
  return (unsigned short)(r >> 16);
}

// pack two f32 -> bf16x2 (round-half-up; 0.5-ulp bound, ties negligible here)
__device__ __forceinline__ unsigned int pack_bf16(float a, float b) {
  union { float f; unsigned int u; } ua, ub; ua.f = a; ub.f = b;
  // dst bytes [0,1,2,3] = [a.b2, a.b3, b.b2, b.b3]
  return __builtin_amdgcn_perm(ub.u + 0x8000u, ua.u + 0x8000u, 0x07060302u);
}

// bump kernel g(u) = exp(1 - 1/(1-u^2+eps)); reference's u>=1-EPS clamp can
// never fire for j<=T-1 (u_max = 1 - 1/horizon), so it is omitted.
__device__ __forceinline__ float kernel_g(float dj, float inv_h) {
  float u = fminf(dj * inv_h, 1.0f - EPSF);
  return __expf(1.0f - 1.0f / (1.0f - u * u + EPSF));
}

typedef void __attribute__((address_space(1)))* gas1;
typedef void __attribute__((address_space(3)))* las3;
// async global->LDS, 16B per lane; LDS dest = wave-uniform base + lane*16
__device__ __forceinline__ void load_lds16(const void* g, void* l) {
  __builtin_amdgcn_global_load_lds((gas1)(g), (las3)(l), 16, 0, 0);
}

// ---------------- fused prep: K rows (rowsum+normalize+pack) AND Xc transpose --------
// grid 8192 x 256. Blocks [0,4096): K row i = blockIdx.x (compute g into LDS,
// block-reduce sum, scale, pack bf16, write full row incl. sub-diagonal zeros).
// Blocks [4096,8192): extract tile -> XcT[b][m][j] = bf16(x[b][j][2m]).
// One launch instead of three (gate/rowsum/kgen/extract) -> saves ~2x15us
// launch overhead and one 32MB round-trip of raw g values.
__global__ __launch_bounds__(256) void prep_kernel(const float* __restrict__ x,
                                                   unsigned short* __restrict__ Kmat,
                                                   unsigned short* __restrict__ XcT) {
  __shared__ float smem[4104];  // krow: [0..4095]=g, [4096..4099]=wave sums
  const int tid = threadIdx.x;
  const int id = blockIdx.x;
  if (id < Tdim) {
    // ---- K row i ----
    const int i = id;
    const float inv_h = __fdividef(1.0f, (float)(Tdim - i));
    float s = 0.0f;
    for (int j = i + tid; j < Tdim; j += 256) {
      const float g = kernel_g((float)(j - i), inv_h);
      smem[j] = g;
      s += g;
    }
#pragma unroll
    for (int off = 32; off; off >>= 1) s += __shfl_down(s, off);
    if ((tid & 63) == 0) smem[4096 + (tid >> 6)] = s;
    __syncthreads();  // g[] complete + wave sums visible
    const float inv_s = __fdividef(
        1.0f, fmaxf(smem[4096] + smem[4097] + smem[4098] + smem[4099], EPSF));
    unsigned short* row = Kmat + (size_t)i * Tdim;
#pragma unroll
    for (int q = tid; q < 512; q += 256) {  // 512 uint4 per row
      const int j8 = q * 8;
      float v[8];
#pragma unroll
      for (int k = 0; k < 8; ++k) {
        const int j = j8 + k;
        v[k] = (j >= i) ? smem[j] * inv_s : 0.0f;  // guard before use: no uninit read
      }
      uint4 pk;
      pk.x = pack_bf16(v[0], v[1]);
      pk.y = pack_bf16(v[2], v[3]);
      pk.z = pack_bf16(v[4], v[5]);
      pk.w = pack_bf16(v[6], v[7]);
      *reinterpret_cast<uint4*>(&row[j8]) = pk;
    }
  } else {
    // ---- extract tile: 64 j x 32 m ----
    const int eid = id - Tdim;
    const int j0 = (eid & 63) * 64;
    const int m0 = ((eid >> 6) & 15) * 32;
    const int b  = eid >> 10;
    unsigned short* Ls = reinterpret_cast<unsigned short*>(smem);  // [32][68]
    const int q = tid & 15;        // float4 chunk along e
    const int jbase = tid >> 4;    // 0..15
#pragma unroll
    for (int it = 0; it < 4; ++it) {
      const int jj = jbase + it * 16;
      const size_t off = ((size_t)(b * Tdim + j0 + jj)) * Edim + 2 * m0 + 4 * q;
      const float4 v = *reinterpret_cast<const float4*>(&x[off]);
      Ls[(2 * q) * 68 + jj]     = f2bf(v.x);   // even channel of m0+2q
      Ls[(2 * q + 1) * 68 + jj] = f2bf(v.z);   // even channel of m0+2q+1
    }
    __syncthreads();
    const int ch = tid & 15;
    const int mb = tid >> 4;
#pragma unroll
    for (int it = 0; it < 2; ++it) {
      const int m = mb + it * 16;
      ushort4 uv;
      uv.x = Ls[m * 68 + 4 * ch];
      uv.y = Ls[m * 68 + 4 * ch + 1];
      uv.z = Ls[m * 68 + 4 * ch + 2];
      uv.w = Ls[m * 68 + 4 * ch + 3];
      *reinterpret_cast<ushort4*>(
          &XcT[((size_t)(b * Mdim + m0 + m)) * Tdim + j0 + 4 * ch]) = uv;
    }
  }
}

// ---------------- GEMM: phi[b,i,m] = K[i,:] @ Xc[b,:,m], fused output write --------
// C-tile 128(i) x 128(m), BK=64, 4 waves, 4x4 frags of 16x16x32 per wave.
// One block OWNS its C-tile. Both A (Kmat) and B (XcT) staged via
// global_load_lds (16B), double-buffered; single barrier per iter (top-of-loop
// vmcnt(0) drain makes tile `cur` resident; prefetch for cur^1 then flies
// under the MFMA+ds_read compute phase). LDS XOR swizzle: 16B slot s of row r
// holds logical chunk s^(r&7) (source-permuted, since global_load_lds dest is
// base+lane*16) -> 0 bank conflicts (verified R2).
// Balance: anti-length pairing. id<256: p=id>>4; else p=31-((id-256)>>4).
// CU c gets blocks {c, c+256} under mod-256 round-robin: iteration count
// (64-2p)+(64-2(31-p)) = 66, exactly uniform (R3's p=id&31 paired equal
// lengths -> CU0 did 128 serial iters = the 87us wall). The 16 blocks sharing
// Kmat rows (mb=0..15) are adjacent ids -> L2/L3 temporal locality.
// Epilogue computes softplus(graw) inline (gate kernel removed).
__global__ __launch_bounds__(256) void gemm_kernel(
    const unsigned short* __restrict__ Kmat,
    const unsigned short* __restrict__ XcT,
    const float* __restrict__ x,
    const float* __restrict__ graw,
    float* __restrict__ out) {
  const int id = blockIdx.x;           // 0..511
  int p;
  if (id < 256) p = id >> 4;
  else          p = 31 - ((id - 256) >> 4);
  const int mb = id & 15;
  const int i0 = p * 128;
  const int m0 = (mb & 3) * 128;
  const int b  = mb >> 2;

  __shared__ unsigned short As[2][128 * 64];  // K rows i0.., swizzled 16B slots
  __shared__ unsigned short Bs[2][128 * 64];  // XcT rows m0.., swizzled
  const int tid = threadIdx.x;
  const int w = tid >> 6;
  const int l = tid & 63;
  f32x4 acc[4][4] = {};
  const int wr = w >> 1, wc = w & 1;
  const unsigned short* Arow = Kmat + (size_t)i0 * Tdim;
  const unsigned short* Brow = XcT + ((size_t)b * Mdim + m0) * Tdim;
  const int srow  = l >> 3;                   // row within 8-row group
  const int sslot = l & 7;                    // linear 16B slot this lane fills
  const int schunk = (sslot ^ srow) * 8;      // swizzled source chunk (bf16 units)

  // preload first tile into buffer 0
#pragma unroll
  for (int t = 0; t < 4; ++t) {
    const int rr = (w * 4 + t) * 8 + srow;
    load_lds16(Arow + (size_t)rr * Tdim + (i0 + schunk), &As[0][(w * 4 + t) * 512]);
    load_lds16(Brow + (size_t)rr * Tdim + (i0 + schunk), &Bs[0][(w * 4 + t) * 512]);
  }

  int cur = 0;
  const int lr16 = l & 15;
  const int kq = l >> 4;  // 0..3: which 16B chunk quarter of the k-dim
  for (int j0 = i0; j0 < Tdim; j0 += 64, cur ^= 1) {
    __syncthreads();  // vmcnt(0) drain: tile `cur` resident; prev reads done
    const int jn = j0 + 64;
    if (jn < Tdim) {  // issue next tile's loads, then compute under them
#pragma unroll
      for (int t = 0; t < 4; ++t) {
        const int rr = (w * 4 + t) * 8 + srow;
        load_lds16(Arow + (size_t)rr * Tdim + (jn + schunk), &As[cur ^ 1][(w * 4 + t) * 512]);
        load_lds16(Brow + (size_t)rr * Tdim + (jn + schunk), &Bs[cur ^ 1][(w * 4 + t) * 512]);
      }
    }
#pragma unroll
    for (int kk = 0; kk < 2; ++kk) {
      bf16x8 af[4], bfr[4];
      const int chunk = kk * 4 + kq;
      const int slot = (chunk ^ (lr16 & 7)) * 8;   // un-swizzle
#pragma unroll
      for (int r = 0; r < 4; ++r)
        af[r] = *reinterpret_cast<const bf16x8*>(&As[cur][(wr * 64 + r * 16 + lr16) * 64 + slot]);
#pragma unroll
      for (int c = 0; c < 4; ++c)
        bfr[c] = *reinterpret_cast<const bf16x8*>(&Bs[cur][(wc * 64 + c * 16 + lr16) * 64 + slot]);
#pragma unroll
      for (int r = 0; r < 4; ++r)
#pragma unroll
        for (int c = 0; c < 4; ++c)
          acc[r][c] = __builtin_amdgcn_mfma_f32_16x16x32_bf16(af[r], bfr[c], acc[r][c], 0, 0, 0);
    }
  }

  // fused epilogue: C/D layout col=lane&15 (m), row=(lane>>4)*4+reg (i).
  // out even = x even (exact fp32 passthrough), odd = phi*softplus(graw[m]).
  const int lr = l & 15;
  const int lq = l >> 4;
  float gm[4];
#pragma unroll
  for (int c = 0; c < 4; ++c) {
    const float v = graw[m0 + wc * 64 + c * 16 + lr];
    gm[c] = fmaxf(v, 0.0f) + __logf(1.0f + __expf(-fabsf(v)));  // stable softplus
  }
#pragma unroll
  for (int r = 0; r < 4; ++r) {
    const int ii = i0 + wr * 64 + r * 16 + lq * 4;
#pragma unroll
    for (int c = 0; c < 4; ++c) {
      const int m = m0 + wc * 64 + c * 16 + lr;
#pragma unroll
      for (int v = 0; v < 4; ++v) {
        const size_t o = ((size_t)(b * Tdim + ii + v)) * Edim + 2 * m;
        const float2 xv = *reinterpret_cast<const float2*>(&x[o]);
        float2 res;
        res.x = xv.x;
        res.y = acc[r][c][v] * gm[c];
        *reinterpret_cast<float2*>(&out[o]) = res;
      }
    }
  }
}

// ---------------- slow-but-correct fallback (only if ws too small) ----------------
__global__ __launch_bounds__(256) void fallback_kernel(const float* __restrict__ x,
                                                       const float* __restrict__ graw,
                                                       float* __restrict__ out) {
  const int i = blockIdx.x, b = blockIdx.y, tid = threadIdx.x;
  const float inv_h = 1.0f / (float)(Tdim - i);
  float s = 0.0f;
  for (int j = i + tid; j < Tdim; j += 256)
    s += kernel_g((float)(j - i), inv_h);
#pragma unroll
  for (int off = 32; off; off >>= 1) s += __shfl_down(s, off);
  __shared__ float red[4];
  __shared__ float sinv_sh;
  if ((tid & 63) == 0) red[tid >> 6] = s;
  __syncthreads();
  if (tid == 0) sinv_sh = 1.0f / (red[0] + red[1] + red[2] + red[3]);
  __syncthreads();
  const float sinv = sinv_sh;
  const float* xb = x + (size_t)b * Tdim * Edim;
  float a0 = 0.0f, a1 = 0.0f;
  const int m0 = tid, m1 = tid + 256;
  for (int j = i; j < Tdim; ++j) {
    const float wgt = kernel_g((float)(j - i), inv_h);
    const float* xr = xb + (size_t)j * Edim;
    a0 += wgt * xr[2 * m0];
    a1 += wgt * xr[2 * m1];
  }
  const float v0 = graw[m0], v1 = graw[m1];
  const float g0 = fmaxf(v0, 0.0f) + log1pf(__expf(-fabsf(v0)));
  const float g1 = fmaxf(v1, 0.0f) + log1pf(__expf(-fabsf(v1)));
  const size_t o = ((size_t)(b * Tdim + i)) * Edim;
  const float* xi = xb + (size_t)i * Edim;
  out[o + 2 * m0]     = xi[2 * m0];
  out[o + 2 * m0 + 1] = a0 * sinv * g0;
  out[o + 2 * m1]     = xi[2 * m1];
  out[o + 2 * m1 + 1] = a1 * sinv * g1;
}

extern "C" void kernel_launch(void* const* d_in, const int* in_sizes, int n_in,
                              void* d_out, int out_size, void* d_ws, size_t ws_size,
                              hipStream_t stream) {
  const float* x = (const float*)d_in[0];
  // d_in[1] is the triu mask: always upper-triangular by construction; folded analytically.
  const float* gate_raw = (const float*)d_in[2];
  float* out = (float*)d_out;

  const size_t XcT_bytes = (size_t)Bdim * Mdim * Tdim * 2;  // 16 MiB
  const size_t K_bytes   = (size_t)Tdim * Tdim * 2;         // 32 MiB
  const size_t need = XcT_bytes + K_bytes;

  if (ws_size < need) {
    fallback_kernel<<<dim3(Tdim, Bdim), 256, 0, stream>>>(x, gate_raw, out);
    return;
  }

  char* ws = (char*)d_ws;
  unsigned short* XcT  = (unsigned short*)ws;
  unsigned short* Kmat = (unsigned short*)(ws + XcT_bytes);

  prep_kernel<<<dim3(2 * Tdim), 256, 0, stream>>>(x, Kmat, XcT);
  gemm_kernel<<<dim3(512), 256, 0, stream>>>(Kmat, XcT, x, gate_raw, out);
}